// Round 4
// baseline (121.157 us; speedup 1.0000x reference)
//
#include <hip/hip_runtime.h>
#include <hip/hip_bf16.h>

// Problem constants (from reference): B=64, N=1024, D=8, S=16
#define BB 64
#define NN 1024
#define DD 8
#define SS 16
#define DS 128           // D*S

typedef __attribute__((ext_vector_type(8))) short short8;
typedef __attribute__((ext_vector_type(4))) float floatx4;

typedef __attribute__((address_space(1))) const unsigned int glds_src;
typedef __attribute__((address_space(3))) unsigned int glds_dst;

static __device__ __forceinline__ unsigned short f2bf(float f) {
    unsigned int u = __float_as_uint(f);
    unsigned int r = (u + 0x7FFFu + ((u >> 16) & 1u)) >> 16;   // RNE
    return (unsigned short)r;
}

// ---------------- Kernel 1: convert matriz_conexao (values exactly 0.0/1.0) to bf16 ----------------
__global__ void convert_M(const float* __restrict__ M, unsigned short* __restrict__ Mb) {
    int i = (blockIdx.x * 256 + threadIdx.x) * 4;
    float4 v = *(const float4*)(M + i);
    unsigned int p0 = (unsigned int)f2bf(v.x) | ((unsigned int)f2bf(v.y) << 16);
    unsigned int p1 = (unsigned int)f2bf(v.z) | ((unsigned int)f2bf(v.w) << 16);
    *(uint2*)(Mb + i) = make_uint2(p0, p1);
}

// ---------------- Kernel 2: x[b][i][ds] fp32  ->  xT[b][ds][i] bf16 (k-contiguous for GEMM B operand) ----
__global__ void transpose_x(const float* __restrict__ x, unsigned short* __restrict__ xT) {
    __shared__ float tile[64 * 68];          // 64x64 fp32 tile, stride 68 (16B-aligned rows)
    const int t  = threadIdx.x;
    const int b  = blockIdx.z;
    const int i0 = blockIdx.x * 64;
    const int c0 = blockIdx.y * 64;
    const float* xb = x + (size_t)b * (NN * DS);

#pragma unroll
    for (int jj = 0; jj < 4; ++jj) {
        int il = (t >> 4) + jj * 16;         // 0..63
        int cl = (t & 15) * 4;               // 0..60
        float4 v = *(const float4*)(xb + (size_t)(i0 + il) * DS + c0 + cl);
        *(float4*)(tile + il * 68 + cl) = v;
    }
    __syncthreads();
    // write 64 bf16 rows (row = ds), each thread writes 16 contiguous i's (32 B)
    int cr  = t >> 2;                        // 0..63 : local ds row
    int iq  = (t & 3) * 16;                  // i sub-offset
    int rot = (t & 3) * 2;                   // j-rotation: breaks the 4-way bank conflict
    unsigned int p[8];
#pragma unroll
    for (int j = 0; j < 8; ++j) {
        int jp = (j + rot) & 7;
        unsigned short lo = f2bf(tile[(iq + 2 * jp + 0) * 68 + cr]);
        unsigned short hi = f2bf(tile[(iq + 2 * jp + 1) * 68 + cr]);
        p[jp] = (unsigned int)lo | ((unsigned int)hi << 16);
    }
    unsigned short* dst = xT + (size_t)b * (NN * DS) + (size_t)(c0 + cr) * NN + i0 + iq;
    *(uint4*)(dst + 0) = make_uint4(p[0], p[1], p[2], p[3]);
    *(uint4*)(dst + 8) = make_uint4(p[4], p[5], p[6], p[7]);
}

// ---------------- Kernel 3: fused GEMM (xm = M @ x_b) + dendrite tanh + soma sigmoid ----------------
// grid = (B, N/128); block 256 (4 waves). Tile: 128 o x 128 ds, K = 1024 over i.
// Pipeline order per iter (the R3 fix): barrier FIRST, then frag ds_reads of the current
// buffer, THEN issue glds prefetch of the next tile, then MFMA. The barrier's vmcnt(0)
// drain thus targets loads issued one full iteration ago (latency covered by compute),
// instead of loads issued 0 cycles ago (R3's mistake).
__global__ __launch_bounds__(256, 2) void gemm_fused(
    const unsigned short* __restrict__ Mb,   // [N][N] bf16, row o, col i (k-contiguous)
    const unsigned short* __restrict__ xT,   // [B][DS][N] bf16, row ds, col i (k-contiguous)
    const float* __restrict__ w_syn,         // [N][D][S]
    const float* __restrict__ b_dend,        // [N][D]
    const float* __restrict__ w_dend,        // [N][D]
    const float* __restrict__ b_soma,        // [N]
    float* __restrict__ out)                 // [B][N]
{
    // 2 x (As 16KB + Bs 16KB) staging + 1 KB soma exchange = 65.5 KB -> 2 blocks/CU
    __shared__ __align__(16) unsigned short As[2][128 * 64];
    __shared__ __align__(16) unsigned short Bs[2][128 * 64];
    __shared__ float ex[128 * 2];

    const int t      = threadIdx.x;
    const int b      = blockIdx.x;            // b fastest -> XCD = b%8: xT[b] pinned per XCD
    const int o_base = blockIdx.y * 128;

    const char* AgB = (const char*)(Mb + (size_t)o_base * NN);
    const char* BgB = (const char*)(xT + (size_t)b * (NN * DS));

    const int lane = t & 63;
    const int w    = t >> 6;
    const int wr   = (w >> 1) * 64;           // wave row offset (o)
    const int wc   = (w & 1) * 64;            // wave col offset (ds)
    const int lm   = lane & 15;
    const int kq   = lane >> 4;               // 0..3

    // staging: row = (w*4+j)*8 + (lane>>3); LDS granule (lane&7) of that row holds
    // global granule (lane&7)^(row&7)  (XOR swizzle; conflict-free, verified R2)
    const int lr = lane >> 3;
    const int lg = (lane & 7) ^ lr;
    int off[4], ldsb[4];
#pragma unroll
    for (int j = 0; j < 4; ++j) {
        off[j]  = ((w * 4 + j) * 8 + lr) * (NN * 2) + lg * 16;
        ldsb[j] = (w * 4 + j) * 1024;          // byte offset into a 16 KB tile
    }

    floatx4 acc[4][4] = {};

    // prologue: stage tile 0 into buffer 0
#pragma unroll
    for (int j = 0; j < 4; ++j) {
        __builtin_amdgcn_global_load_lds((glds_src*)(AgB + off[j]),
                                         (glds_dst*)((char*)As[0] + ldsb[j]), 16, 0, 0);
        __builtin_amdgcn_global_load_lds((glds_src*)(BgB + off[j]),
                                         (glds_dst*)((char*)Bs[0] + ldsb[j]), 16, 0, 0);
    }

#pragma unroll
    for (int kt = 0; kt < 16; ++kt) {
        // barrier: drains vmcnt(0) = the glds issued LAST iteration (latency covered),
        // and lgkmcnt(0) = everyone's frag reads of the buffer we're about to overwrite.
        __syncthreads();

        const unsigned short* Ac = As[kt & 1];
        const unsigned short* Bc = Bs[kt & 1];

        // fragment reads for the whole tile (both ks halves) BEFORE issuing prefetch
        short8 af[2][4], bf[2][4];
#pragma unroll
        for (int ks = 0; ks < 2; ++ks) {
            const int g = (((ks * 4 + kq) ^ (lm & 7)) * 8);   // swizzled ushort offset in row
#pragma unroll
            for (int r = 0; r < 4; ++r)
                af[ks][r] = *(const short8*)(Ac + (wr + r * 16 + lm) * 64 + g);
#pragma unroll
            for (int c = 0; c < 4; ++c)
                bf[ks][c] = *(const short8*)(Bc + (wc + c * 16 + lm) * 64 + g);
        }

        // prefetch tile kt+1 into the other buffer (drained at NEXT iter's barrier)
        if (kt < 15) {
            const int kb = (kt + 1) * 128;     // byte offset along k
            const int nb = (kt + 1) & 1;
#pragma unroll
            for (int j = 0; j < 4; ++j) {
                __builtin_amdgcn_global_load_lds((glds_src*)(AgB + off[j] + kb),
                                                 (glds_dst*)((char*)As[nb] + ldsb[j]), 16, 0, 0);
                __builtin_amdgcn_global_load_lds((glds_src*)(BgB + off[j] + kb),
                                                 (glds_dst*)((char*)Bs[nb] + ldsb[j]), 16, 0, 0);
            }
        }

#pragma unroll
        for (int ks = 0; ks < 2; ++ks)
#pragma unroll
            for (int r = 0; r < 4; ++r)
#pragma unroll
                for (int c = 0; c < 4; ++c)
                    acc[r][c] = __builtin_amdgcn_mfma_f32_16x16x32_bf16(af[ks][r], bf[ks][c], acc[r][c], 0, 0, 0);
    }

    // ---- register epilogue (verified R3) ----
    // C/D layout: for acc[r][c][reg]: o = o_base+wr+r*16+kq*4+reg, ds = wc+c*16+lm
    // => dendrite d = (w&1)*4 + c, synapse s = lm. Butterfly over lm (within quad-16).
    float keep[4];
#pragma unroll
    for (int r = 0; r < 4; ++r) {
#pragma unroll
        for (int rg = 0; rg < 4; ++rg) {
            const int o = o_base + wr + r * 16 + kq * 4 + rg;
#pragma unroll
            for (int c = 0; c < 4; ++c) {
                const int d = (w & 1) * 4 + c;
                float p = acc[r][c][rg] * w_syn[o * DS + d * SS + lm];
                p += __shfl_xor(p, 1);
                p += __shfl_xor(p, 2);
                p += __shfl_xor(p, 4);
                p += __shfl_xor(p, 8);         // all 16 lanes of the quad now hold sum_s
                if (lm == r * 4 + rg) keep[c] = p;
            }
        }
    }
    // each lane finalizes one o: lane lm encodes (r=lm>>2, reg=lm&3)
    {
        const int o_loc = wr + (lm >> 2) * 16 + kq * 4 + (lm & 3);
        const int o     = o_base + o_loc;
        float part = 0.f;
#pragma unroll
        for (int c = 0; c < 4; ++c) {
            const int d = (w & 1) * 4 + c;
            float pre = keep[c] + b_dend[o * DD + d];
            part += tanhf(pre) * w_dend[o * DD + d];
        }
        ex[o_loc * 2 + (w & 1)] = part;        // waves (0,1) cover o 0..63, (2,3) o 64..127
    }
    __syncthreads();
    if (t < 128) {
        float soma = ex[t * 2] + ex[t * 2 + 1] + b_soma[o_base + t];
        out[(size_t)b * NN + o_base + t] = 1.f / (1.f + __expf(-soma));
    }
}

extern "C" void kernel_launch(void* const* d_in, const int* in_sizes, int n_in,
                              void* d_out, int out_size, void* d_ws, size_t ws_size,
                              hipStream_t stream) {
    const float* x      = (const float*)d_in[0];   // [B,N,D,S]
    const float* M      = (const float*)d_in[1];   // [N,N]
    const float* w_syn  = (const float*)d_in[2];   // [N,D,S]
    const float* b_dend = (const float*)d_in[3];   // [N,D]
    const float* w_dend = (const float*)d_in[4];   // [N,D]
    const float* b_soma = (const float*)d_in[5];   // [N]
    float* out = (float*)d_out;

    unsigned short* xT = (unsigned short*)d_ws;                 // [B][DS][N] bf16 : 16 MiB
    unsigned short* Mb = xT + (size_t)BB * NN * DS;             // [N][N]   bf16 :  2 MiB

    convert_M  <<<dim3(NN * NN / (256 * 4)), 256, 0, stream>>>(M, Mb);
    transpose_x<<<dim3(NN / 64, DS / 64, BB), 256, 0, stream>>>(x, xT);
    gemm_fused <<<dim3(BB, NN / 128), 256, 0, stream>>>(Mb, xT, w_syn, b_dend, w_dend, b_soma, out);
}

// Round 5
// 111.510 us; speedup vs baseline: 1.0865x; 1.0865x over previous
//
#include <hip/hip_runtime.h>
#include <hip/hip_bf16.h>

// Problem constants (from reference): B=64, N=1024, D=8, S=16
#define BB 64
#define NN 1024
#define DD 8
#define SS 16
#define DS 128           // D*S

typedef __attribute__((ext_vector_type(8))) short short8;
typedef __attribute__((ext_vector_type(4))) float floatx4;

typedef __attribute__((address_space(1))) const unsigned int glds_src;
typedef __attribute__((address_space(3))) unsigned int glds_dst;

static __device__ __forceinline__ unsigned short f2bf(float f) {
    unsigned int u = __float_as_uint(f);
    unsigned int r = (u + 0x7FFFu + ((u >> 16) & 1u)) >> 16;   // RNE
    return (unsigned short)r;
}

// ---------------- Kernel 1: convert matriz_conexao (values exactly 0.0/1.0) to bf16 ----------------
__global__ void convert_M(const float* __restrict__ M, unsigned short* __restrict__ Mb) {
    int i = (blockIdx.x * 256 + threadIdx.x) * 4;
    float4 v = *(const float4*)(M + i);
    unsigned int p0 = (unsigned int)f2bf(v.x) | ((unsigned int)f2bf(v.y) << 16);
    unsigned int p1 = (unsigned int)f2bf(v.z) | ((unsigned int)f2bf(v.w) << 16);
    *(uint2*)(Mb + i) = make_uint2(p0, p1);
}

// ---------------- Kernel 2: x[b][i][ds] fp32  ->  xT[b][ds][i] bf16 (k-contiguous for GEMM B operand) ----
__global__ void transpose_x(const float* __restrict__ x, unsigned short* __restrict__ xT) {
    __shared__ float tile[64 * 68];          // 64x64 fp32 tile, stride 68 (16B-aligned rows)
    const int t  = threadIdx.x;
    const int b  = blockIdx.z;
    const int i0 = blockIdx.x * 64;
    const int c0 = blockIdx.y * 64;
    const float* xb = x + (size_t)b * (NN * DS);

#pragma unroll
    for (int jj = 0; jj < 4; ++jj) {
        int il = (t >> 4) + jj * 16;         // 0..63
        int cl = (t & 15) * 4;               // 0..60
        float4 v = *(const float4*)(xb + (size_t)(i0 + il) * DS + c0 + cl);
        *(float4*)(tile + il * 68 + cl) = v;
    }
    __syncthreads();
    // write 64 bf16 rows (row = ds), each thread writes 16 contiguous i's (32 B)
    int cr  = t >> 2;                        // 0..63 : local ds row
    int iq  = (t & 3) * 16;                  // i sub-offset
    int rot = (t & 3) * 2;                   // j-rotation: breaks the 4-way bank conflict
    unsigned int p[8];
#pragma unroll
    for (int j = 0; j < 8; ++j) {
        int jp = (j + rot) & 7;
        unsigned short lo = f2bf(tile[(iq + 2 * jp + 0) * 68 + cr]);
        unsigned short hi = f2bf(tile[(iq + 2 * jp + 1) * 68 + cr]);
        p[jp] = (unsigned int)lo | ((unsigned int)hi << 16);
    }
    unsigned short* dst = xT + (size_t)b * (NN * DS) + (size_t)(c0 + cr) * NN + i0 + iq;
    *(uint4*)(dst + 0) = make_uint4(p[0], p[1], p[2], p[3]);
    *(uint4*)(dst + 8) = make_uint4(p[4], p[5], p[6], p[7]);
}

// ---------------- Kernel 3: fused GEMM (xm = M @ x_b) + dendrite tanh + soma sigmoid ----------------
// grid = (B, N/128); block 256 (4 waves). Tile: 128 o x 128 ds, K = 1024 over i.
// K-loop: R2's empirically-best single-buffered two-barrier glds loop (dbuf variants
// regressed in R3/R4 — m99/m100 redux). The new lever is OCCUPANCY: register epilogue
// (no Cs tile) drops LDS 66->33 KB, and __launch_bounds__(256,3) gives 3 blocks/CU
// (12 waves). Per m114, other resident blocks' MFMA covers a stalled block's barrier
// drain — coverage scales with resident blocks.
__global__ __launch_bounds__(256, 3) void gemm_fused(
    const unsigned short* __restrict__ Mb,   // [N][N] bf16, row o, col i (k-contiguous)
    const unsigned short* __restrict__ xT,   // [B][DS][N] bf16, row ds, col i (k-contiguous)
    const float* __restrict__ w_syn,         // [N][D][S]
    const float* __restrict__ b_dend,        // [N][D]
    const float* __restrict__ w_dend,        // [N][D]
    const float* __restrict__ b_soma,        // [N]
    float* __restrict__ out)                 // [B][N]
{
    __shared__ __align__(16) unsigned short As[128 * 64];   // 16 KB (o rows)
    __shared__ __align__(16) unsigned short Bs[128 * 64];   // 16 KB (ds rows)
    __shared__ float ex[128 * 2];                           // 1 KB soma exchange

    const int t      = threadIdx.x;
    const int b      = blockIdx.x;            // b fastest -> XCD = b%8: xT[b] pinned per XCD
    const int o_base = blockIdx.y * 128;

    const char* AgB = (const char*)(Mb + (size_t)o_base * NN);
    const char* BgB = (const char*)(xT + (size_t)b * (NN * DS));

    const int lane = t & 63;
    const int w    = t >> 6;
    const int wr   = (w >> 1) * 64;           // wave row offset (o)
    const int wc   = (w & 1) * 64;            // wave col offset (ds)
    const int lm   = lane & 15;
    const int kq   = lane >> 4;               // 0..3

    // staging: row = (w*4+j)*8 + (lane>>3); LDS granule (lane&7) of that row holds
    // global granule (lane&7)^(row&7)  (XOR swizzle; conflict-free, verified R2)
    const int lr = lane >> 3;
    const int lg = (lane & 7) ^ lr;
    int off[4], ldsb[4];
#pragma unroll
    for (int j = 0; j < 4; ++j) {
        off[j]  = ((w * 4 + j) * 8 + lr) * (NN * 2) + lg * 16;
        ldsb[j] = (w * 4 + j) * 1024;          // byte offset into a 16 KB tile
    }

    floatx4 acc[4][4] = {};

    for (int kt = 0; kt < 16; ++kt) {
        const int kb = kt * 128;               // byte offset along k within a row
        __syncthreads();                       // previous tile's frag reads done
#pragma unroll
        for (int j = 0; j < 4; ++j) {
            __builtin_amdgcn_global_load_lds((glds_src*)(AgB + off[j] + kb),
                                             (glds_dst*)((char*)As + ldsb[j]), 16, 0, 0);
            __builtin_amdgcn_global_load_lds((glds_src*)(BgB + off[j] + kb),
                                             (glds_dst*)((char*)Bs + ldsb[j]), 16, 0, 0);
        }
        __syncthreads();                       // drains vmcnt(0): tile staged
#pragma unroll
        for (int ks = 0; ks < 2; ++ks) {
            short8 af[4], bf[4];
            const int g = (((ks * 4 + kq) ^ (lm & 7)) * 8);   // swizzled ushort offset in row
#pragma unroll
            for (int r = 0; r < 4; ++r)
                af[r] = *(const short8*)(As + (wr + r * 16 + lm) * 64 + g);
#pragma unroll
            for (int c = 0; c < 4; ++c)
                bf[c] = *(const short8*)(Bs + (wc + c * 16 + lm) * 64 + g);
#pragma unroll
            for (int r = 0; r < 4; ++r)
#pragma unroll
                for (int c = 0; c < 4; ++c)
                    acc[r][c] = __builtin_amdgcn_mfma_f32_16x16x32_bf16(af[r], bf[c], acc[r][c], 0, 0, 0);
        }
    }

    // ---- register epilogue (verified R3/R4) ----
    // C/D layout: for acc[r][c][reg]: o = o_base+wr+r*16+kq*4+reg, ds = wc+c*16+lm
    // => dendrite d = (w&1)*4 + c, synapse s = lm. Butterfly over lm (within quad-16).
    float keep[4];
#pragma unroll
    for (int r = 0; r < 4; ++r) {
#pragma unroll
        for (int rg = 0; rg < 4; ++rg) {
            const int o = o_base + wr + r * 16 + kq * 4 + rg;
#pragma unroll
            for (int c = 0; c < 4; ++c) {
                const int d = (w & 1) * 4 + c;
                float p = acc[r][c][rg] * w_syn[o * DS + d * SS + lm];
                p += __shfl_xor(p, 1);
                p += __shfl_xor(p, 2);
                p += __shfl_xor(p, 4);
                p += __shfl_xor(p, 8);         // all 16 lanes of the quad now hold sum_s
                if (lm == r * 4 + rg) keep[c] = p;
            }
        }
    }
    // each lane finalizes one o: lane lm encodes (r=lm>>2, reg=lm&3)
    {
        const int o_loc = wr + (lm >> 2) * 16 + kq * 4 + (lm & 3);
        const int o     = o_base + o_loc;
        float part = 0.f;
#pragma unroll
        for (int c = 0; c < 4; ++c) {
            const int d = (w & 1) * 4 + c;
            float pre = keep[c] + b_dend[o * DD + d];
            part += tanhf(pre) * w_dend[o * DD + d];
        }
        ex[o_loc * 2 + (w & 1)] = part;        // waves (0,1) cover o 0..63, (2,3) o 64..127
    }
    __syncthreads();
    if (t < 128) {
        float soma = ex[t * 2] + ex[t * 2 + 1] + b_soma[o_base + t];
        out[(size_t)b * NN + o_base + t] = 1.f / (1.f + __expf(-soma));
    }
}

extern "C" void kernel_launch(void* const* d_in, const int* in_sizes, int n_in,
                              void* d_out, int out_size, void* d_ws, size_t ws_size,
                              hipStream_t stream) {
    const float* x      = (const float*)d_in[0];   // [B,N,D,S]
    const float* M      = (const float*)d_in[1];   // [N,N]
    const float* w_syn  = (const float*)d_in[2];   // [N,D,S]
    const float* b_dend = (const float*)d_in[3];   // [N,D]
    const float* w_dend = (const float*)d_in[4];   // [N,D]
    const float* b_soma = (const float*)d_in[5];   // [N]
    float* out = (float*)d_out;

    unsigned short* xT = (unsigned short*)d_ws;                 // [B][DS][N] bf16 : 16 MiB
    unsigned short* Mb = xT + (size_t)BB * NN * DS;             // [N][N]   bf16 :  2 MiB

    convert_M  <<<dim3(NN * NN / (256 * 4)), 256, 0, stream>>>(M, Mb);
    transpose_x<<<dim3(NN / 64, DS / 64, BB), 256, 0, stream>>>(x, xT);
    gemm_fused <<<dim3(BB, NN / 128), 256, 0, stream>>>(Mb, xT, w_syn, b_dend, w_dend, b_soma, out);
}

// Round 7
// 110.395 us; speedup vs baseline: 1.0975x; 1.0101x over previous
//
#include <hip/hip_runtime.h>
#include <hip/hip_bf16.h>

// Problem constants (from reference): B=64, N=1024, D=8, S=16
#define BB 64
#define NN 1024
#define DD 8
#define SS 16
#define DS 128           // D*S

typedef __attribute__((ext_vector_type(8))) short short8;
typedef __attribute__((ext_vector_type(4))) float floatx4;

typedef __attribute__((address_space(1))) const unsigned int glds_src;
typedef __attribute__((address_space(3))) unsigned int glds_dst;

static __device__ __forceinline__ unsigned short f2bf(float f) {
    unsigned int u = __float_as_uint(f);
    unsigned int r = (u + 0x7FFFu + ((u >> 16) & 1u)) >> 16;   // RNE
    return (unsigned short)r;
}

// ---------------- Kernel 1: convert matriz_conexao (values exactly 0.0/1.0) to bf16 ----------------
__global__ void convert_M(const float* __restrict__ M, unsigned short* __restrict__ Mb) {
    int i = (blockIdx.x * 256 + threadIdx.x) * 4;
    float4 v = *(const float4*)(M + i);
    unsigned int p0 = (unsigned int)f2bf(v.x) | ((unsigned int)f2bf(v.y) << 16);
    unsigned int p1 = (unsigned int)f2bf(v.z) | ((unsigned int)f2bf(v.w) << 16);
    *(uint2*)(Mb + i) = make_uint2(p0, p1);
}

// ---------------- Kernel 2: x[b][i][ds] fp32  ->  xT[b][ds][i] bf16 (k-contiguous for GEMM B operand) ----
__global__ void transpose_x(const float* __restrict__ x, unsigned short* __restrict__ xT) {
    __shared__ float tile[64 * 68];          // 64x64 fp32 tile, stride 68 (16B-aligned rows)
    const int t  = threadIdx.x;
    const int b  = blockIdx.z;
    const int i0 = blockIdx.x * 64;
    const int c0 = blockIdx.y * 64;
    const float* xb = x + (size_t)b * (NN * DS);

#pragma unroll
    for (int jj = 0; jj < 4; ++jj) {
        int il = (t >> 4) + jj * 16;         // 0..63
        int cl = (t & 15) * 4;               // 0..60
        float4 v = *(const float4*)(xb + (size_t)(i0 + il) * DS + c0 + cl);
        *(float4*)(tile + il * 68 + cl) = v;
    }
    __syncthreads();
    // write 64 bf16 rows (row = ds), each thread writes 16 contiguous i's (32 B)
    int cr  = t >> 2;                        // 0..63 : local ds row
    int iq  = (t & 3) * 16;                  // i sub-offset
    int rot = (t & 3) * 2;                   // j-rotation: breaks the 4-way bank conflict
    unsigned int p[8];
#pragma unroll
    for (int j = 0; j < 8; ++j) {
        int jp = (j + rot) & 7;
        unsigned short lo = f2bf(tile[(iq + 2 * jp + 0) * 68 + cr]);
        unsigned short hi = f2bf(tile[(iq + 2 * jp + 1) * 68 + cr]);
        p[jp] = (unsigned int)lo | ((unsigned int)hi << 16);
    }
    unsigned short* dst = xT + (size_t)b * (NN * DS) + (size_t)(c0 + cr) * NN + i0 + iq;
    *(uint4*)(dst + 0) = make_uint4(p[0], p[1], p[2], p[3]);
    *(uint4*)(dst + 8) = make_uint4(p[4], p[5], p[6], p[7]);
}

// ---------------- Kernel 3: fused GEMM (xm = M @ x_b) + dendrite tanh + soma sigmoid ----------------
// grid = (B, N/128); block 256 (4 waves). Tile: 128 o x 128 ds, K = 1024 over i.
// BK=128 variant of the R2/R5-proven skeleton: 8 K-iterations instead of 16 -> half the
// barrier pairs, double the work per barrier. Single-buffered, two barriers per iter
// (every dbuf/pipelining variant regressed: R3/R4). LDS 2x32 KB + 1 KB = 65.5 KB -> 2 blk/CU
// (same occupancy R2 ran at; R5 showed 3 blk/CU is neutral).
// Swizzle (256 B rows, 16 granules): LDS slot s of row r holds global granule s^(r&15);
// glds writes stay dense 1 KB; frag ds_read_b128 banks alias exactly 2-way (free, m136).
__global__ __launch_bounds__(256, 2) void gemm_fused(
    const unsigned short* __restrict__ Mb,   // [N][N] bf16, row o, col i (k-contiguous)
    const unsigned short* __restrict__ xT,   // [B][DS][N] bf16, row ds, col i (k-contiguous)
    const float* __restrict__ w_syn,         // [N][D][S]
    const float* __restrict__ b_dend,        // [N][D]
    const float* __restrict__ w_dend,        // [N][D]
    const float* __restrict__ b_soma,        // [N]
    float* __restrict__ out)                 // [B][N]
{
    __shared__ __align__(16) unsigned short As[128 * 128];  // 32 KB (o rows, BK=128)
    __shared__ __align__(16) unsigned short Bs[128 * 128];  // 32 KB (ds rows, BK=128)
    __shared__ float ex[128 * 2];                           // 1 KB soma exchange

    const int t      = threadIdx.x;
    const int b      = blockIdx.x;            // b fastest -> XCD = b%8: xT[b] pinned per XCD
    const int o_base = blockIdx.y * 128;

    const char* AgB = (const char*)(Mb + (size_t)o_base * NN);
    const char* BgB = (const char*)(xT + (size_t)b * (NN * DS));

    const int lane = t & 63;
    const int w    = t >> 6;
    const int wr   = (w >> 1) * 64;           // wave row offset (o)
    const int wc   = (w & 1) * 64;            // wave col offset (ds)
    const int lm   = lane & 15;
    const int kq   = lane >> 4;               // 0..3

    // staging: glds j (0..7) of wave w covers rows (w*8+j)*4 + (lane>>4), 16 granules/row.
    // Source granule for LDS slot (lane&15) is (lane&15)^(row&15)  (XOR-16 swizzle).
    int off[8], ldsb[8];
#pragma unroll
    for (int j = 0; j < 8; ++j) {
        const int row = (w * 8 + j) * 4 + (lane >> 4);
        const int sg  = (lane & 15) ^ (row & 15);
        off[j]  = row * (NN * 2) + sg * 16;
        ldsb[j] = (w * 8 + j) * 1024;          // wave-uniform base; +lane*16 is implicit
    }

    floatx4 acc[4][4] = {};

    for (int kt = 0; kt < 8; ++kt) {
        const int kb = kt * 256;               // byte offset along k within a row (BK=128)
        __syncthreads();                       // previous tile's frag reads done
#pragma unroll
        for (int j = 0; j < 8; ++j) {
            __builtin_amdgcn_global_load_lds((glds_src*)(AgB + off[j] + kb),
                                             (glds_dst*)((char*)As + ldsb[j]), 16, 0, 0);
            __builtin_amdgcn_global_load_lds((glds_src*)(BgB + off[j] + kb),
                                             (glds_dst*)((char*)Bs + ldsb[j]), 16, 0, 0);
        }
        __syncthreads();                       // drains vmcnt(0): tile staged
#pragma unroll
        for (int ks = 0; ks < 4; ++ks) {
            short8 af[4], bf[4];
            const int g = (((ks * 4 + kq) ^ lm) * 8);   // swizzled ushort offset in 128-row
#pragma unroll
            for (int r = 0; r < 4; ++r)
                af[r] = *(const short8*)(As + (wr + r * 16 + lm) * 128 + g);
#pragma unroll
            for (int c = 0; c < 4; ++c)
                bf[c] = *(const short8*)(Bs + (wc + c * 16 + lm) * 128 + g);
#pragma unroll
            for (int r = 0; r < 4; ++r)
#pragma unroll
                for (int c = 0; c < 4; ++c)
                    acc[r][c] = __builtin_amdgcn_mfma_f32_16x16x32_bf16(af[r], bf[c], acc[r][c], 0, 0, 0);
        }
    }

    // ---- register epilogue (verified R3-R5) ----
    // C/D layout: for acc[r][c][reg]: o = o_base+wr+r*16+kq*4+reg, ds = wc+c*16+lm
    // => dendrite d = (w&1)*4 + c, synapse s = lm. Butterfly over lm (within quad-16).
    float keep[4];
#pragma unroll
    for (int r = 0; r < 4; ++r) {
#pragma unroll
        for (int rg = 0; rg < 4; ++rg) {
            const int o = o_base + wr + r * 16 + kq * 4 + rg;
#pragma unroll
            for (int c = 0; c < 4; ++c) {
                const int d = (w & 1) * 4 + c;
                float p = acc[r][c][rg] * w_syn[o * DS + d * SS + lm];
                p += __shfl_xor(p, 1);
                p += __shfl_xor(p, 2);
                p += __shfl_xor(p, 4);
                p += __shfl_xor(p, 8);         // all 16 lanes of the quad now hold sum_s
                if (lm == r * 4 + rg) keep[c] = p;
            }
        }
    }
    // each lane finalizes one o: lane lm encodes (r=lm>>2, reg=lm&3)
    {
        const int o_loc = wr + (lm >> 2) * 16 + kq * 4 + (lm & 3);
        const int o     = o_base + o_loc;
        float part = 0.f;
#pragma unroll
        for (int c = 0; c < 4; ++c) {
            const int d = (w & 1) * 4 + c;
            float pre = keep[c] + b_dend[o * DD + d];
            part += tanhf(pre) * w_dend[o * DD + d];
        }
        ex[o_loc * 2 + (w & 1)] = part;        // waves (0,1) cover o 0..63, (2,3) o 64..127
    }
    __syncthreads();
    if (t < 128) {
        float soma = ex[t * 2] + ex[t * 2 + 1] + b_soma[o_base + t];
        out[(size_t)b * NN + o_base + t] = 1.f / (1.f + __expf(-soma));
    }
}

extern "C" void kernel_launch(void* const* d_in, const int* in_sizes, int n_in,
                              void* d_out, int out_size, void* d_ws, size_t ws_size,
                              hipStream_t stream) {
    const float* x      = (const float*)d_in[0];   // [B,N,D,S]
    const float* M      = (const float*)d_in[1];   // [N,N]
    const float* w_syn  = (const float*)d_in[2];   // [N,D,S]
    const float* b_dend = (const float*)d_in[3];   // [N,D]
    const float* w_dend = (const float*)d_in[4];   // [N,D]
    const float* b_soma = (const float*)d_in[5];   // [N]
    float* out = (float*)d_out;

    unsigned short* xT = (unsigned short*)d_ws;                 // [B][DS][N] bf16 : 16 MiB
    unsigned short* Mb = xT + (size_t)BB * NN * DS;             // [N][N]   bf16 :  2 MiB

    convert_M  <<<dim3(NN * NN / (256 * 4)), 256, 0, stream>>>(M, Mb);
    transpose_x<<<dim3(NN / 64, DS / 64, BB), 256, 0, stream>>>(x, xT);
    gemm_fused <<<dim3(BB, NN / 128), 256, 0, stream>>>(Mb, xT, w_syn, b_dend, w_dend, b_soma, out);
}

// Round 8
// 108.614 us; speedup vs baseline: 1.1155x; 1.0164x over previous
//
#include <hip/hip_runtime.h>
#include <hip/hip_bf16.h>

// Problem constants (from reference): B=64, N=1024, D=8, S=16
#define BB 64
#define NN 1024
#define DD 8
#define SS 16
#define DS 128           // D*S

typedef __attribute__((ext_vector_type(8))) short short8;
typedef __attribute__((ext_vector_type(4))) float floatx4;

typedef __attribute__((address_space(1))) const unsigned int glds_src;
typedef __attribute__((address_space(3))) unsigned int glds_dst;

static __device__ __forceinline__ unsigned short f2bf(float f) {
    unsigned int u = __float_as_uint(f);
    unsigned int r = (u + 0x7FFFu + ((u >> 16) & 1u)) >> 16;   // RNE
    return (unsigned short)r;
}

// ---------------- Kernel 1: merged prepass ----------------
// blocks [0,1024): convert matriz_conexao (values exactly 0.0/1.0) fp32 -> bf16
// blocks [1024,3072): x[b][i][ds] fp32 -> xT[b][ds][i] bf16 (k-contiguous GEMM B operand)
// Merged so convert's 6 MB rides inside the transpose's HBM-bound window (one graph node fewer).
__global__ void prepass(const float* __restrict__ x, unsigned short* __restrict__ xT,
                        const float* __restrict__ M, unsigned short* __restrict__ Mb) {
    __shared__ float tile[64 * 68];          // 64x64 fp32 tile, stride 68 (16B-aligned rows)
    const int t = threadIdx.x;

    if (blockIdx.x < 1024) {                 // ---- convert_M part ----
        int i = (blockIdx.x * 256 + t) * 4;
        float4 v = *(const float4*)(M + i);
        unsigned int p0 = (unsigned int)f2bf(v.x) | ((unsigned int)f2bf(v.y) << 16);
        unsigned int p1 = (unsigned int)f2bf(v.z) | ((unsigned int)f2bf(v.w) << 16);
        *(uint2*)(Mb + i) = make_uint2(p0, p1);
        return;
    }

    // ---- transpose part: decompose flattened id exactly like the old (16,2,64) grid ----
    const int bid = blockIdx.x - 1024;
    const int i0 = (bid & 15) * 64;          // old blockIdx.x
    const int c0 = ((bid >> 4) & 1) * 64;    // old blockIdx.y
    const int b  = bid >> 5;                 // old blockIdx.z
    const float* xb = x + (size_t)b * (NN * DS);

#pragma unroll
    for (int jj = 0; jj < 4; ++jj) {
        int il = (t >> 4) + jj * 16;         // 0..63
        int cl = (t & 15) * 4;               // 0..60
        float4 v = *(const float4*)(xb + (size_t)(i0 + il) * DS + c0 + cl);
        *(float4*)(tile + il * 68 + cl) = v;
    }
    __syncthreads();
    // write 64 bf16 rows (row = ds), each thread writes 16 contiguous i's (32 B)
    int cr  = t >> 2;                        // 0..63 : local ds row
    int iq  = (t & 3) * 16;                  // i sub-offset
    int rot = (t & 3) * 2;                   // j-rotation: breaks the 4-way bank conflict
    unsigned int p[8];
#pragma unroll
    for (int j = 0; j < 8; ++j) {
        int jp = (j + rot) & 7;
        unsigned short lo = f2bf(tile[(iq + 2 * jp + 0) * 68 + cr]);
        unsigned short hi = f2bf(tile[(iq + 2 * jp + 1) * 68 + cr]);
        p[jp] = (unsigned int)lo | ((unsigned int)hi << 16);
    }
    unsigned short* dst = xT + (size_t)b * (NN * DS) + (size_t)(c0 + cr) * NN + i0 + iq;
    *(uint4*)(dst + 0) = make_uint4(p[0], p[1], p[2], p[3]);
    *(uint4*)(dst + 8) = make_uint4(p[4], p[5], p[6], p[7]);
}

// ---------------- Kernel 2: fused GEMM (xm = M @ x_b) + dendrite tanh + soma sigmoid ----------------
// BYTE-IDENTICAL to R7 (best: 110.4 us). grid = (B, N/128); block 256 (4 waves).
// Tile 128 o x 128 ds, BK=128 (8 iters), single-buffered two-barrier glds loop.
// This K-loop is at the m97-class structural plateau (R2/R3/R4/R5/R7 all ~25-28 us):
// LDS ~15 us + MFMA 8.3 us + L2 7.4 us overlapped at ~60% by the barrier chain;
// per learn_hip m131-m141 no HIP-source-level change moves it.
__global__ __launch_bounds__(256, 2) void gemm_fused(
    const unsigned short* __restrict__ Mb,   // [N][N] bf16, row o, col i (k-contiguous)
    const unsigned short* __restrict__ xT,   // [B][DS][N] bf16, row ds, col i (k-contiguous)
    const float* __restrict__ w_syn,         // [N][D][S]
    const float* __restrict__ b_dend,        // [N][D]
    const float* __restrict__ w_dend,        // [N][D]
    const float* __restrict__ b_soma,        // [N]
    float* __restrict__ out)                 // [B][N]
{
    __shared__ __align__(16) unsigned short As[128 * 128];  // 32 KB (o rows, BK=128)
    __shared__ __align__(16) unsigned short Bs[128 * 128];  // 32 KB (ds rows, BK=128)
    __shared__ float ex[128 * 2];                           // 1 KB soma exchange

    const int t      = threadIdx.x;
    const int b      = blockIdx.x;            // b fastest -> XCD = b%8: xT[b] pinned per XCD
    const int o_base = blockIdx.y * 128;

    const char* AgB = (const char*)(Mb + (size_t)o_base * NN);
    const char* BgB = (const char*)(xT + (size_t)b * (NN * DS));

    const int lane = t & 63;
    const int w    = t >> 6;
    const int wr   = (w >> 1) * 64;           // wave row offset (o)
    const int wc   = (w & 1) * 64;            // wave col offset (ds)
    const int lm   = lane & 15;
    const int kq   = lane >> 4;               // 0..3

    // staging: glds j (0..7) of wave w covers rows (w*8+j)*4 + (lane>>4), 16 granules/row.
    // Source granule for LDS slot (lane&15) is (lane&15)^(row&15)  (XOR-16 swizzle).
    int off[8], ldsb[8];
#pragma unroll
    for (int j = 0; j < 8; ++j) {
        const int row = (w * 8 + j) * 4 + (lane >> 4);
        const int sg  = (lane & 15) ^ (row & 15);
        off[j]  = row * (NN * 2) + sg * 16;
        ldsb[j] = (w * 8 + j) * 1024;          // wave-uniform base; +lane*16 is implicit
    }

    floatx4 acc[4][4] = {};

    for (int kt = 0; kt < 8; ++kt) {
        const int kb = kt * 256;               // byte offset along k within a row (BK=128)
        __syncthreads();                       // previous tile's frag reads done
#pragma unroll
        for (int j = 0; j < 8; ++j) {
            __builtin_amdgcn_global_load_lds((glds_src*)(AgB + off[j] + kb),
                                             (glds_dst*)((char*)As + ldsb[j]), 16, 0, 0);
            __builtin_amdgcn_global_load_lds((glds_src*)(BgB + off[j] + kb),
                                             (glds_dst*)((char*)Bs + ldsb[j]), 16, 0, 0);
        }
        __syncthreads();                       // drains vmcnt(0): tile staged
#pragma unroll
        for (int ks = 0; ks < 4; ++ks) {
            short8 af[4], bf[4];
            const int g = (((ks * 4 + kq) ^ lm) * 8);   // swizzled ushort offset in 128-row
#pragma unroll
            for (int r = 0; r < 4; ++r)
                af[r] = *(const short8*)(As + (wr + r * 16 + lm) * 128 + g);
#pragma unroll
            for (int c = 0; c < 4; ++c)
                bf[c] = *(const short8*)(Bs + (wc + c * 16 + lm) * 128 + g);
#pragma unroll
            for (int r = 0; r < 4; ++r)
#pragma unroll
                for (int c = 0; c < 4; ++c)
                    acc[r][c] = __builtin_amdgcn_mfma_f32_16x16x32_bf16(af[r], bf[c], acc[r][c], 0, 0, 0);
        }
    }

    // ---- register epilogue (verified R3-R7) ----
    // C/D layout: for acc[r][c][reg]: o = o_base+wr+r*16+kq*4+reg, ds = wc+c*16+lm
    // => dendrite d = (w&1)*4 + c, synapse s = lm. Butterfly over lm (within quad-16).
    float keep[4];
#pragma unroll
    for (int r = 0; r < 4; ++r) {
#pragma unroll
        for (int rg = 0; rg < 4; ++rg) {
            const int o = o_base + wr + r * 16 + kq * 4 + rg;
#pragma unroll
            for (int c = 0; c < 4; ++c) {
                const int d = (w & 1) * 4 + c;
                float p = acc[r][c][rg] * w_syn[o * DS + d * SS + lm];
                p += __shfl_xor(p, 1);
                p += __shfl_xor(p, 2);
                p += __shfl_xor(p, 4);
                p += __shfl_xor(p, 8);         // all 16 lanes of the quad now hold sum_s
                if (lm == r * 4 + rg) keep[c] = p;
            }
        }
    }
    // each lane finalizes one o: lane lm encodes (r=lm>>2, reg=lm&3)
    {
        const int o_loc = wr + (lm >> 2) * 16 + kq * 4 + (lm & 3);
        const int o     = o_base + o_loc;
        float part = 0.f;
#pragma unroll
        for (int c = 0; c < 4; ++c) {
            const int d = (w & 1) * 4 + c;
            float pre = keep[c] + b_dend[o * DD + d];
            part += tanhf(pre) * w_dend[o * DD + d];
        }
        ex[o_loc * 2 + (w & 1)] = part;        // waves (0,1) cover o 0..63, (2,3) o 64..127
    }
    __syncthreads();
    if (t < 128) {
        float soma = ex[t * 2] + ex[t * 2 + 1] + b_soma[o_base + t];
        out[(size_t)b * NN + o_base + t] = 1.f / (1.f + __expf(-soma));
    }
}

extern "C" void kernel_launch(void* const* d_in, const int* in_sizes, int n_in,
                              void* d_out, int out_size, void* d_ws, size_t ws_size,
                              hipStream_t stream) {
    const float* x      = (const float*)d_in[0];   // [B,N,D,S]
    const float* M      = (const float*)d_in[1];   // [N,N]
    const float* w_syn  = (const float*)d_in[2];   // [N,D,S]
    const float* b_dend = (const float*)d_in[3];   // [N,D]
    const float* w_dend = (const float*)d_in[4];   // [N,D]
    const float* b_soma = (const float*)d_in[5];   // [N]
    float* out = (float*)d_out;

    unsigned short* xT = (unsigned short*)d_ws;                 // [B][DS][N] bf16 : 16 MiB
    unsigned short* Mb = xT + (size_t)BB * NN * DS;             // [N][N]   bf16 :  2 MiB

    prepass   <<<dim3(1024 + 2048), 256, 0, stream>>>(x, xT, M, Mb);
    gemm_fused<<<dim3(BB, NN / 128), 256, 0, stream>>>(Mb, xT, w_syn, b_dend, w_dend, b_soma, out);
}